// Round 8
// baseline (239.599 us; speedup 1.0000x reference)
//
#include <hip/hip_runtime.h>
#include <hip/hip_bf16.h>

// Problem geometry (fixed by setup_inputs)
#define BATCH 4
#define DZ 96
#define DY 192
#define DX 192
#define ZS (DY * DX)            // 36864
#define SVOL ((size_t)DZ * ZS)  // 3538944 voxels per batch item
#define NTOT ((double)(4.0 * (double)SVOL))
#define VPT 4                   // voxels per thread (float4-coalesced)
#define BLOCK 256
#define BLOCKS_PER_BATCH ((int)(SVOL / (VPT * BLOCK)))  // 3456
#define GRID (BATCH * BLOCKS_PER_BATCH)                 // 13824

#define WORDS_TOTAL ((int)((BATCH * SVOL) / 64))   // 221184 u64 words
#define MAP_BYTES ((size_t)WORDS_TOTAL * 8)        // 1769472 B per bitmap
#define PART_BYTES ((size_t)GRID * 16)             // float4 per block
#define WS_NEED (PART_BYTES + 3 * MAP_BYTES)

// Exact expanding-box search for voxels whose entire (in-bounds) 26-neighborhood
// matches their own class (expected ~0 on Bernoulli targets; exactness fallback).
__device__ __noinline__ int far_dist(const int* __restrict__ T, size_t bOff,
                                     int z, int y, int x, int tv) {
    for (int r = 2; r <= 20; ++r) {
        int zlo = max(z - r, 0), zhi = min(z + r, DZ - 1);
        int ylo = max(y - r, 0), yhi = min(y + r, DY - 1);
        int xlo = max(x - r, 0), xhi = min(x + r, DX - 1);
        for (int zz = zlo; zz <= zhi; ++zz)
            for (int yy = ylo; yy <= yhi; ++yy) {
                const int* rp = T + bOff + (size_t)zz * ZS + (size_t)yy * DX;
                for (int xx = xlo; xx <= xhi; ++xx)
                    if (rp[xx] != tv) return r;
            }
    }
    return 21;
}

// ---------------- pack kernel: int32 targets -> 3 bitmaps (proven exact) ----
__global__ __launch_bounds__(256) void pack_kernel(
    const int* __restrict__ tgt,
    unsigned long long* __restrict__ Tm,
    unsigned long long* __restrict__ Om,
    unsigned long long* __restrict__ Am)
{
    const int tid = blockIdx.x * 256 + threadIdx.x;
    const int t = tgt[tid];
    const unsigned long long b = __ballot(t != 0);
    const int w = tid >> 6;                       // u64 word index
    const int lane = threadIdx.x & 63;
    const int xw = (w % 3) * 64;                  // word position in its 192-row
    const size_t base = ((size_t)w) << 6;

    int ev = 0;                                   // edge voxel value (lanes 0,63)
    if (lane == 0 && xw != 0)    ev = tgt[base - 1];
    if (lane == 63 && xw != 128) ev = tgt[base + 64];
    const int eL0 = __shfl(ev, 0);
    const int eR0 = __shfl(ev, 63);

    const unsigned long long eLor  = (xw != 0   && eL0 != 0) ? 1ull : 0ull;
    const unsigned long long eRor  = (xw != 128 && eR0 != 0) ? (1ull << 63) : 0ull;
    const unsigned long long eLand = (xw == 0   || eL0 != 0) ? 1ull : 0ull;
    const unsigned long long eRand = (xw == 128 || eR0 != 0) ? (1ull << 63) : 0ull;

    const unsigned long long horOR  = b | (b << 1) | (b >> 1) | eLor | eRor;
    const unsigned long long horAND = b & ((b << 1) | eLand) & ((b >> 1) | eRand);

    if (lane == 0) { Tm[w] = b; Om[w] = horOR; Am[w] = horAND; }
}

// ---------------- main kernel: 4 vox/thread, fully coalesced ----------------
__global__ __launch_bounds__(BLOCK) void boundary_loss_kernel(
    const float* __restrict__ inp,
    const int* __restrict__ tgt,
    const unsigned long long* __restrict__ Om,
    const unsigned long long* __restrict__ Am,
    const unsigned long long* __restrict__ Tm,
    float4* __restrict__ P)          // per-block (s1, s2, fg, 0)
{
    const int b = blockIdx.x / BLOCKS_PER_BATCH;
    const size_t bOff = (size_t)b * SVOL;
    const int gid = blockIdx.x * BLOCK + threadIdx.x;
    const size_t vox = (size_t)gid * VPT;
    const int rem = (int)(vox - bOff);
    const int z = rem / ZS;
    const int ry = rem - z * ZS;
    const int y = ry / DX;
    const int x0 = ry - y * DX;                  // multiple of 4

    const size_t rowC = (size_t)(b * DZ + z) * DY + y;   // global bitmap row
    const int bx = x0 >> 3;                      // byte within 24-byte row
    const int nib = x0 & 4;                      // nibble shift (0 or 4)
    const unsigned char* O8 = (const unsigned char*)Om;
    const unsigned char* A8 = (const unsigned char*)Am;
    const unsigned char* T8 = (const unsigned char*)Tm;

    const int dzo[3] = {(z > 0) ? -1 : 0, 0, (z < DZ - 1) ? 1 : 0};
    const int vzf[3] = {z > 0, 1, z < DZ - 1};
    const int dyo[3] = {(y > 0) ? -1 : 0, 0, (y < DY - 1) ? 1 : 0};
    const int vyf[3] = {y > 0, 1, y < DY - 1};

    unsigned int or9 = 0u, and9 = 0xFFu;
    #pragma unroll
    for (int iz = 0; iz < 3; ++iz) {
        #pragma unroll
        for (int iy = 0; iy < 3; ++iy) {
            const size_t ba = (rowC + (long)dzo[iz] * DY + dyo[iy]) * 24 + bx;
            const unsigned int o = O8[ba];
            const unsigned int a = A8[ba];
            const unsigned int m = (vzf[iz] & vyf[iy]) ? 0xFFu : 0u;
            or9  |= o & m;
            and9 &= a | ~m;
        }
    }
    and9 &= 0xFFu;
    const unsigned int diff4 = ((or9 ^ and9) >> nib) & 0xFu; // opposite-neighbor bits
    const unsigned int tc4 = ((unsigned int)T8[rowC * 24 + bx] >> nib) & 0xFu;

    // probs_fg = sigmoid(x1 - x0); one perfectly-coalesced float4 per channel
    const size_t sp = (size_t)z * ZS + (size_t)y * DX + x0;
    const float* i0 = inp + ((size_t)(2 * b)) * SVOL + sp;
    const float4 A = *(const float4*)(i0);
    const float4 B = *(const float4*)(i0 + SVOL);
    const float c0[4] = {A.x, A.y, A.z, A.w};
    const float c1[4] = {B.x, B.y, B.z, B.w};

    float s1 = 0.f, s2 = 0.f;
    #pragma unroll
    for (int i = 0; i < VPT; ++i) {
        const float e   = __expf(c0[i] - c1[i]);
        const float sig = __builtin_amdgcn_rcpf(1.0f + e);
        const int ti = (int)((tc4 >> i) & 1u);
        float val = (float)ti;                   // D==1 closed form
        if (!((diff4 >> i) & 1u)) {              // astronomically rare exact path
            const int D = far_dist(tgt, bOff, z, y, x0 + i, ti);
            const int mm = min(D - 1, 20);
            val = ti ? (1.0f - (float)mm) : (float)mm;
        }
        s1 = fmaf(sig, val, s1);
        s2 += sig;
    }
    float s3 = (tc4 != 0u) ? 1.f : 0.f;          // foreground presence

    // wave reduce (64 lanes), then block reduce via LDS, single plain store
    #pragma unroll
    for (int off = 32; off > 0; off >>= 1) {
        s1 += __shfl_down(s1, off);
        s2 += __shfl_down(s2, off);
        s3 += __shfl_down(s3, off);
    }
    __shared__ float red1[BLOCK / 64], red2[BLOCK / 64], red3[BLOCK / 64];
    const int lane = threadIdx.x & 63, wid = threadIdx.x >> 6;
    if (lane == 0) { red1[wid] = s1; red2[wid] = s2; red3[wid] = s3; }
    __syncthreads();
    if (threadIdx.x == 0) {
        P[blockIdx.x] = make_float4(red1[0] + red1[1] + red1[2] + red1[3],
                                    red2[0] + red2[1] + red2[2] + red2[3],
                                    red3[0] + red3[1] + red3[2] + red3[3], 0.f);
    }
}

// ---------------- final reduction: 13824 partials -> scalar loss ------------
__global__ __launch_bounds__(1024) void reduce_kernel(
    const float4* __restrict__ P, float* __restrict__ out)
{
    const int tid = threadIdx.x;
    const int lane = tid & 63, wid = tid >> 6;
    __shared__ double L1[16], L2[16], L3[16];
    double tot = 0.0;

    for (int b = 0; b < BATCH; ++b) {
        double d1 = 0.0, d2 = 0.0, d3 = 0.0;
        for (int i = tid; i < BLOCKS_PER_BATCH; i += 1024) {
            float4 p = P[b * BLOCKS_PER_BATCH + i];
            d1 += p.x; d2 += p.y; d3 += p.z;
        }
        #pragma unroll
        for (int off = 32; off > 0; off >>= 1) {
            d1 += __shfl_down(d1, off);
            d2 += __shfl_down(d2, off);
            d3 += __shfl_down(d3, off);
        }
        if (lane == 0) { L1[wid] = d1; L2[wid] = d2; L3[wid] = d3; }
        __syncthreads();
        if (tid == 0) {
            double t1 = 0.0, t2 = 0.0, t3 = 0.0;
            #pragma unroll
            for (int w = 0; w < 16; ++w) { t1 += L1[w]; t2 += L2[w]; t3 += L3[w]; }
            tot += (t3 > 0.0) ? t1 : t2;   // no_fg batch: dist_map == 1 everywhere
        }
        __syncthreads();
    }
    if (tid == 0) out[0] = (float)(tot / NTOT);
}

extern "C" void kernel_launch(void* const* d_in, const int* in_sizes, int n_in,
                              void* d_out, int out_size, void* d_ws, size_t ws_size,
                              hipStream_t stream) {
    const float* inp = (const float*)d_in[0];
    const int*   tgt = (const int*)d_in[1];
    float* out = (float*)d_out;
    float4* P = (float4*)d_ws;                    // 13824 * 16 B partials

    unsigned long long* Tm = (unsigned long long*)((char*)d_ws + PART_BYTES);
    unsigned long long* Om = Tm + WORDS_TOTAL;
    unsigned long long* Am = Om + WORDS_TOTAL;
    hipLaunchKernelGGL(pack_kernel, dim3((BATCH * (int)SVOL) / 256), dim3(256),
                       0, stream, tgt, Tm, Om, Am);
    hipLaunchKernelGGL(boundary_loss_kernel, dim3(GRID), dim3(BLOCK), 0, stream,
                       inp, tgt, Om, Am, Tm, P);
    hipLaunchKernelGGL(reduce_kernel, dim3(1), dim3(1024), 0, stream, P, out);
}

// Round 9
// 239.344 us; speedup vs baseline: 1.0011x; 1.0011x over previous
//
#include <hip/hip_runtime.h>
#include <hip/hip_bf16.h>

// Problem geometry (fixed by setup_inputs)
#define BATCH 4
#define DZ 96
#define DY 192
#define DX 192
#define ZS (DY * DX)            // 36864
#define SVOL ((size_t)DZ * ZS)  // 3538944 voxels per batch item
#define NTOT ((double)(4.0 * (double)SVOL))
#define VPT 4                   // voxels per thread per iteration (float4)
#define BLOCK 256

// main: 3456 blocks x 256 thr x 4 vox = SVOL exactly -> iteration == batch
#define MBLOCKS 3456
// pack: 1728 fat blocks x 32 iterations cover all 14.16M voxels
#define PBLOCKS 1728
#define PITER 32

#define WORDS_TOTAL ((int)((BATCH * SVOL) / 64))   // 221184 u64 words
#define MAP_BYTES ((size_t)WORDS_TOTAL * 8)        // 1769472 B per bitmap
#define PART_BYTES ((size_t)(BATCH * MBLOCKS) * 16)

// Exact expanding-box search for voxels whose entire (in-bounds) 26-neighborhood
// matches their own class (expected ~0 on Bernoulli targets; exactness fallback).
__device__ __noinline__ int far_dist(const int* __restrict__ T, size_t bOff,
                                     int z, int y, int x, int tv) {
    for (int r = 2; r <= 20; ++r) {
        int zlo = max(z - r, 0), zhi = min(z + r, DZ - 1);
        int ylo = max(y - r, 0), yhi = min(y + r, DY - 1);
        int xlo = max(x - r, 0), xhi = min(x + r, DX - 1);
        for (int zz = zlo; zz <= zhi; ++zz)
            for (int yy = ylo; yy <= yhi; ++yy) {
                const int* rp = T + bOff + (size_t)zz * ZS + (size_t)yy * DX;
                for (int xx = xlo; xx <= xhi; ++xx)
                    if (rp[xx] != tv) return r;
            }
    }
    return 21;
}

// ---------------- pack kernel: grid-stride, int32 targets -> 3 bitmaps ------
__global__ __launch_bounds__(BLOCK) void pack_kernel(
    const int* __restrict__ tgt,
    unsigned long long* __restrict__ Tm,
    unsigned long long* __restrict__ Om,
    unsigned long long* __restrict__ Am)
{
    const int lane = threadIdx.x & 63;
    #pragma unroll 1
    for (int it = 0; it < PITER; ++it) {
        const int tid = it * (PBLOCKS * BLOCK) + blockIdx.x * BLOCK + threadIdx.x;
        const int t = tgt[tid];
        const unsigned long long b = __ballot(t != 0);
        const int w = tid >> 6;                   // u64 word index
        const int xw = (w % 3) * 64;              // word position in its 192-row
        const size_t base = ((size_t)w) << 6;

        int ev = 0;                               // edge voxel value (lanes 0,63)
        if (lane == 0 && xw != 0)    ev = tgt[base - 1];
        if (lane == 63 && xw != 128) ev = tgt[base + 64];
        const int eL0 = __shfl(ev, 0);
        const int eR0 = __shfl(ev, 63);

        const unsigned long long eLor  = (xw != 0   && eL0 != 0) ? 1ull : 0ull;
        const unsigned long long eRor  = (xw != 128 && eR0 != 0) ? (1ull << 63) : 0ull;
        const unsigned long long eLand = (xw == 0   || eL0 != 0) ? 1ull : 0ull;
        const unsigned long long eRand = (xw == 128 || eR0 != 0) ? (1ull << 63) : 0ull;

        const unsigned long long horOR  = b | (b << 1) | (b >> 1) | eLor | eRor;
        const unsigned long long horAND = b & ((b << 1) | eLand) & ((b >> 1) | eRand);

        if (lane == 0) { Tm[w] = b; Om[w] = horOR; Am[w] = horAND; }
    }
}

// ---------------- main kernel: addr math amortized over the 4 batches -------
__global__ __launch_bounds__(BLOCK) void boundary_loss_kernel(
    const float* __restrict__ inp,
    const int* __restrict__ tgt,
    const unsigned long long* __restrict__ Om,
    const unsigned long long* __restrict__ Am,
    const unsigned long long* __restrict__ Tm,
    float4* __restrict__ P)          // per-(batch,block) partials
{
    const int gid = blockIdx.x * BLOCK + threadIdx.x;
    const int rem = gid * VPT;                   // voxel offset within a batch
    const int z = rem / ZS;
    const int ry = rem - z * ZS;
    const int y = ry / DX;
    const int x0 = ry - y * DX;                  // multiple of 4

    const int rowB = z * DY + y;                 // row index within a batch
    const int bx = x0 >> 3;                      // byte within 24-byte bitmap row
    const int nib = x0 & 4;                      // nibble shift (0 or 4)
    const unsigned char* O8 = (const unsigned char*)Om;
    const unsigned char* A8 = (const unsigned char*)Am;
    const unsigned char* T8 = (const unsigned char*)Tm;

    // 9 neighborhood byte offsets relative to batch bitmap base (clamped+masked)
    const int dzo[3] = {(z > 0) ? -1 : 0, 0, (z < DZ - 1) ? 1 : 0};
    const int vzf[3] = {z > 0, 1, z < DZ - 1};
    const int dyo[3] = {(y > 0) ? -1 : 0, 0, (y < DY - 1) ? 1 : 0};
    const int vyf[3] = {y > 0, 1, y < DY - 1};
    int  noff[9];
    unsigned int nmask[9];
    #pragma unroll
    for (int iz = 0; iz < 3; ++iz)
        #pragma unroll
        for (int iy = 0; iy < 3; ++iy) {
            noff[iz * 3 + iy]  = (rowB + dzo[iz] * DY + dyo[iy]) * 24 + bx;
            nmask[iz * 3 + iy] = (vzf[iz] & vyf[iy]) ? 0xFFu : 0u;
        }
    const int toff = rowB * 24 + bx;

    __shared__ float red1[BLOCK / 64], red2[BLOCK / 64], red3[BLOCK / 64];
    const int lane = threadIdx.x & 63, wid = threadIdx.x >> 6;

    #pragma unroll 1
    for (int b = 0; b < BATCH; ++b) {            // iteration == batch
        const size_t mapB = (size_t)b * (DZ * DY * 24);  // batch bitmap base (bytes)
        unsigned int or9 = 0u, and9 = 0xFFu;
        #pragma unroll
        for (int k = 0; k < 9; ++k) {
            const size_t ba = mapB + noff[k];
            or9  |= (unsigned int)O8[ba] & nmask[k];
            and9 &= (unsigned int)A8[ba] | ~nmask[k];
        }
        and9 &= 0xFFu;
        const unsigned int diff4 = ((or9 ^ and9) >> nib) & 0xFu;
        const unsigned int tc4 = ((unsigned int)T8[mapB + toff] >> nib) & 0xFu;

        // probs_fg = sigmoid(x1 - x0); perfectly lane-coalesced float4 loads
        const float* i0 = inp + ((size_t)(2 * b)) * SVOL + rem;
        const float4 A = *(const float4*)(i0);
        const float4 Bv = *(const float4*)(i0 + SVOL);
        const float c0[4] = {A.x, A.y, A.z, A.w};
        const float c1[4] = {Bv.x, Bv.y, Bv.z, Bv.w};

        float s1 = 0.f, s2 = 0.f;
        #pragma unroll
        for (int i = 0; i < VPT; ++i) {
            const float e   = __expf(c0[i] - c1[i]);
            const float sig = __builtin_amdgcn_rcpf(1.0f + e);
            const int ti = (int)((tc4 >> i) & 1u);
            float val = (float)ti;               // D==1 closed form
            if (!((diff4 >> i) & 1u)) {          // astronomically rare exact path
                const int D = far_dist(tgt, (size_t)b * SVOL, z, y, x0 + i, ti);
                const int mm = min(D - 1, 20);
                val = ti ? (1.0f - (float)mm) : (float)mm;
            }
            s1 = fmaf(sig, val, s1);
            s2 += sig;
        }
        float s3 = (tc4 != 0u) ? 1.f : 0.f;      // foreground presence

        // wave reduce, block reduce, one plain store per (batch, block)
        #pragma unroll
        for (int off = 32; off > 0; off >>= 1) {
            s1 += __shfl_down(s1, off);
            s2 += __shfl_down(s2, off);
            s3 += __shfl_down(s3, off);
        }
        if (lane == 0) { red1[wid] = s1; red2[wid] = s2; red3[wid] = s3; }
        __syncthreads();
        if (threadIdx.x == 0) {
            P[b * MBLOCKS + blockIdx.x] =
                make_float4(red1[0] + red1[1] + red1[2] + red1[3],
                            red2[0] + red2[1] + red2[2] + red2[3],
                            red3[0] + red3[1] + red3[2] + red3[3], 0.f);
        }
        __syncthreads();                         // red arrays reused next batch
    }
}

// ---------------- final reduction: 4 x 3456 partials -> scalar loss ---------
__global__ __launch_bounds__(1024) void reduce_kernel(
    const float4* __restrict__ P, float* __restrict__ out)
{
    const int tid = threadIdx.x;
    const int lane = tid & 63, wid = tid >> 6;
    __shared__ double L1[16], L2[16], L3[16];
    double tot = 0.0;

    for (int b = 0; b < BATCH; ++b) {
        double d1 = 0.0, d2 = 0.0, d3 = 0.0;
        for (int i = tid; i < MBLOCKS; i += 1024) {
            float4 p = P[b * MBLOCKS + i];
            d1 += p.x; d2 += p.y; d3 += p.z;
        }
        #pragma unroll
        for (int off = 32; off > 0; off >>= 1) {
            d1 += __shfl_down(d1, off);
            d2 += __shfl_down(d2, off);
            d3 += __shfl_down(d3, off);
        }
        if (lane == 0) { L1[wid] = d1; L2[wid] = d2; L3[wid] = d3; }
        __syncthreads();
        if (tid == 0) {
            double t1 = 0.0, t2 = 0.0, t3 = 0.0;
            #pragma unroll
            for (int w = 0; w < 16; ++w) { t1 += L1[w]; t2 += L2[w]; t3 += L3[w]; }
            tot += (t3 > 0.0) ? t1 : t2;   // no_fg batch: dist_map == 1 everywhere
        }
        __syncthreads();
    }
    if (tid == 0) out[0] = (float)(tot / NTOT);
}

extern "C" void kernel_launch(void* const* d_in, const int* in_sizes, int n_in,
                              void* d_out, int out_size, void* d_ws, size_t ws_size,
                              hipStream_t stream) {
    const float* inp = (const float*)d_in[0];
    const int*   tgt = (const int*)d_in[1];
    float* out = (float*)d_out;

    float4* P = (float4*)d_ws;                    // 4*3456 float4 partials
    unsigned long long* Tm = (unsigned long long*)((char*)d_ws + PART_BYTES);
    unsigned long long* Om = Tm + WORDS_TOTAL;
    unsigned long long* Am = Om + WORDS_TOTAL;

    hipLaunchKernelGGL(pack_kernel, dim3(PBLOCKS), dim3(BLOCK), 0, stream,
                       tgt, Tm, Om, Am);
    hipLaunchKernelGGL(boundary_loss_kernel, dim3(MBLOCKS), dim3(BLOCK), 0, stream,
                       inp, tgt, Om, Am, Tm, P);
    hipLaunchKernelGGL(reduce_kernel, dim3(1), dim3(1024), 0, stream, P, out);
}